// Round 3
// baseline (196.307 us; speedup 1.0000x reference)
//
#include <hip/hip_runtime.h>

typedef __attribute__((ext_vector_type(4))) float f32x4;
typedef __attribute__((ext_vector_type(8))) short bf16x8;
typedef __attribute__((ext_vector_type(4))) unsigned int u32x4;
typedef unsigned short ushort_t;

#define B_ROWS 65536
#define L_DIM  256
#define H_IN_D 300
#define H_PAD  320
#define BM     32
#define LDH    328   // hbuf row stride in ushorts (320 + 8 pad)  -> 20992 B
#define LDV    264   // vbuf row stride in ushorts (256 + 8 pad)  -> 16896 B
#define NTH    256

__device__ __forceinline__ ushort_t f2bf(float f) {
  unsigned u = __builtin_bit_cast(unsigned, f);
  unsigned r = u + 0x7fffu + ((u >> 16) & 1u);   // RNE, no NaN in data
  return (ushort_t)(r >> 16);
}
__device__ __forceinline__ float bflo(unsigned u) { return __builtin_bit_cast(float, u << 16); }
__device__ __forceinline__ float bfhi(unsigned u) { return __builtin_bit_cast(float, u & 0xffff0000u); }

// ---------------- weight pre-conversion (once per launch) ----------------
__global__ void cvt_w(const float* __restrict__ W0, const float* __restrict__ Ws,
                      ushort_t* __restrict__ W0b, ushort_t* __restrict__ Wsb) {
  int i = blockIdx.x * blockDim.x + threadIdx.x;
  int stride = gridDim.x * blockDim.x;
  for (int t = i; t < 256 * H_PAD; t += stride) {
    int n = t / H_PAD, k = t - n * H_PAD;
    W0b[t] = (k < H_IN_D) ? f2bf(W0[n * H_IN_D + k]) : (ushort_t)0;
  }
  for (int t = i; t < 3 * 256 * 256; t += stride) Wsb[t] = f2bf(Ws[t]);
}

// ---------------- fused flow kernel (BM=32) ----------------
// GEMM per wave: 2 m-tiles x 4 n-tiles of 16x16, c0 = wave*64.
// A frag: lane reads A[mt*16 + r][ks*32 + g*8 ..+7] (LDS bf16)
// B frag: lane reads W[c0+nt*16+r][ks*32 + g*8 ..+7] (global bf16, L2-resident)
// C/D layout (m89-verified): row = g*4 + j, col = r within each 16x16 tile.
template<int KSTEPS, int LDA, int LDO>
__device__ __forceinline__ void gemm_stage(
    const ushort_t* __restrict__ Alds,
    const ushort_t* __restrict__ Bg, int ldb,
    const float* __restrict__ bias,
    ushort_t* __restrict__ Olds,
    int wave, int r, int g)
{
  f32x4 acc[2][4];
#pragma unroll
  for (int mt = 0; mt < 2; ++mt)
#pragma unroll
    for (int nt = 0; nt < 4; ++nt) { acc[mt][nt][0] = 0.f; acc[mt][nt][1] = 0.f; acc[mt][nt][2] = 0.f; acc[mt][nt][3] = 0.f; }

  const int c0 = wave * 64;
  const ushort_t* Abase = Alds + r * LDA + g * 8;
  const ushort_t* Bbase = Bg + (c0 + r) * ldb + g * 8;

#pragma unroll
  for (int ks = 0; ks < KSTEPS; ++ks) {
    bf16x8 b[4];
#pragma unroll
    for (int nt = 0; nt < 4; ++nt) b[nt] = *(const bf16x8*)(Bbase + nt * 16 * ldb + ks * 32);
    bf16x8 a[2];
#pragma unroll
    for (int mt = 0; mt < 2; ++mt) a[mt] = *(const bf16x8*)(Abase + mt * 16 * LDA + ks * 32);
#pragma unroll
    for (int mt = 0; mt < 2; ++mt) {
      acc[mt][0] = __builtin_amdgcn_mfma_f32_16x16x32_bf16(a[mt], b[0], acc[mt][0], 0, 0, 0);
      acc[mt][1] = __builtin_amdgcn_mfma_f32_16x16x32_bf16(a[mt], b[1], acc[mt][1], 0, 0, 0);
      acc[mt][2] = __builtin_amdgcn_mfma_f32_16x16x32_bf16(a[mt], b[2], acc[mt][2], 0, 0, 0);
      acc[mt][3] = __builtin_amdgcn_mfma_f32_16x16x32_bf16(a[mt], b[3], acc[mt][3], 0, 0, 0);
    }
  }

  // epilogue: +bias, cvt bf16, write v tile to LDS
#pragma unroll
  for (int nt = 0; nt < 4; ++nt) {
    float bv = bias[c0 + nt * 16 + r];
#pragma unroll
    for (int mt = 0; mt < 2; ++mt) {
#pragma unroll
      for (int j = 0; j < 4; ++j) {
        float val = acc[mt][nt][j] + bv;
        Olds[(mt * 16 + g * 4 + j) * LDO + c0 + nt * 16 + r] = f2bf(val);
      }
    }
  }
}

// Householder: z -= 2 v (v.z)/(v.v). Row = wave*8 + (lane>>3); lane owns
// cols (lane&7)*32 .. +31. Reduce across the 8 lanes sharing a row via
// shfl_xor 1,2,4.
template<int LDVx>
__device__ __forceinline__ void dot_update(const ushort_t* __restrict__ V,
                                           int wave, int lane, float (&zr)[32])
{
  const int zrow = wave * 8 + (lane >> 3);
  const int cb = (lane & 7) * 32;
  const ushort_t* vp = V + zrow * LDVx + cb;
  float vz = 0.f, vv = 0.f;
#pragma unroll
  for (int jb = 0; jb < 4; ++jb) {
    u32x4 q = *(const u32x4*)(vp + jb * 8);
#pragma unroll
    for (int w = 0; w < 4; ++w) {
      unsigned u = q[w];
      float f0 = bflo(u), f1 = bfhi(u);
      int i = jb * 8 + w * 2;
      vz = fmaf(f0, zr[i], vz);     vv = fmaf(f0, f0, vv);
      vz = fmaf(f1, zr[i + 1], vz); vv = fmaf(f1, f1, vv);
    }
  }
  vz += __shfl_xor(vz, 1); vv += __shfl_xor(vv, 1);
  vz += __shfl_xor(vz, 2); vv += __shfl_xor(vv, 2);
  vz += __shfl_xor(vz, 4); vv += __shfl_xor(vv, 4);
  float a = 2.f * vz / vv;
#pragma unroll
  for (int jb = 0; jb < 4; ++jb) {
    u32x4 q = *(const u32x4*)(vp + jb * 8);
#pragma unroll
    for (int w = 0; w < 4; ++w) {
      unsigned u = q[w];
      int i = jb * 8 + w * 2;
      zr[i]     = fmaf(-a, bflo(u), zr[i]);
      zr[i + 1] = fmaf(-a, bfhi(u), zr[i + 1]);
    }
  }
}

__global__ __launch_bounds__(NTH, 4) void flow_fused(
    const float* __restrict__ z, const float* __restrict__ h,
    const ushort_t* __restrict__ W0b, const float* __restrict__ b0,
    const ushort_t* __restrict__ Wsb, const float* __restrict__ bs,
    float* __restrict__ out)
{
  // LDS: vb0 [32][264] bf16 + hbuf [32][328] bf16 (hbuf doubles as second v buf)
  __shared__ __align__(16) ushort_t smem[BM * LDV + BM * LDH];  // 37888 B -> 4 blocks/CU
  ushort_t* vb0  = smem;
  ushort_t* hbuf = smem + BM * LDV;

  const int tid  = threadIdx.x;
  const int wave = tid >> 6;
  const int lane = tid & 63;
  const int r    = lane & 15;
  const int g    = lane >> 4;
  const int row0 = blockIdx.x * BM;

  // ---- load h tile -> hbuf (bf16, K padded 300->320 with zeros) ----
  for (int row = wave; row < BM; row += 4) {
    const float* hrow = h + (row0 + row) * H_IN_D;
#pragma unroll
    for (int cc = 0; cc < 5; ++cc) {
      int c = lane + cc * 64;
      float v = (c < H_IN_D) ? hrow[c] : 0.f;
      hbuf[row * LDH + c] = f2bf(v);
    }
  }

  // ---- load z tile into registers (row = wave*8 + lane>>3, 32 cols/lane) ----
  float zr[32];
  const int zrow = wave * 8 + (lane >> 3);
  const int cb = (lane & 7) * 32;
  {
    const float* zp = z + (row0 + zrow) * L_DIM + cb;
#pragma unroll
    for (int j = 0; j < 8; ++j) {
      f32x4 v = *(const f32x4*)(zp + j * 4);
      zr[j * 4 + 0] = v[0]; zr[j * 4 + 1] = v[1];
      zr[j * 4 + 2] = v[2]; zr[j * 4 + 3] = v[3];
    }
  }

  __syncthreads();

  // stage 1: v1 = h @ W0^T + b0   (K=320 padded), hbuf -> vb0
  gemm_stage<10, LDH, LDV>(hbuf, W0b, H_PAD, b0, vb0, wave, r, g);
  __syncthreads();
  dot_update<LDV>(vb0, wave, lane, zr);

  // stages 2..4: ping-pong vb0 <-> hbuf (h is dead after stage 1).
  // One barrier per stage suffices: between a gemm's epilogue writes and the
  // next readers; dot reads only the buffer written before the last barrier.
#pragma unroll
  for (int s = 0; s < 3; ++s) {
    const ushort_t* Wp = Wsb + s * 256 * 256;
    const float*    bp = bs + s * 256;
    if ((s & 1) == 0) {
      gemm_stage<8, LDV, LDH>(vb0, Wp, 256, bp, hbuf, wave, r, g);
      __syncthreads();
      dot_update<LDH>(hbuf, wave, lane, zr);
    } else {
      gemm_stage<8, LDH, LDV>(hbuf, Wp, 256, bp, vb0, wave, r, g);
      __syncthreads();
      dot_update<LDV>(vb0, wave, lane, zr);
    }
  }

  // ---- store z ----
  {
    float* op = out + (row0 + zrow) * L_DIM + cb;
#pragma unroll
    for (int j = 0; j < 8; ++j) {
      f32x4 v;
      v[0] = zr[j * 4 + 0]; v[1] = zr[j * 4 + 1];
      v[2] = zr[j * 4 + 2]; v[3] = zr[j * 4 + 3];
      *(f32x4*)(op + j * 4) = v;
    }
  }
}

extern "C" void kernel_launch(void* const* d_in, const int* in_sizes, int n_in,
                              void* d_out, int out_size, void* d_ws, size_t ws_size,
                              hipStream_t stream) {
  const float* z  = (const float*)d_in[0];
  const float* h  = (const float*)d_in[1];
  const float* W0 = (const float*)d_in[2];
  const float* b0 = (const float*)d_in[3];
  const float* Ws = (const float*)d_in[4];
  const float* bs = (const float*)d_in[5];
  float* out = (float*)d_out;

  ushort_t* W0b = (ushort_t*)d_ws;            // 256*320 bf16 = 163840 B
  ushort_t* Wsb = W0b + 256 * H_PAD;          // 3*256*256 bf16 = 393216 B

  hipLaunchKernelGGL(cvt_w, dim3(256), dim3(NTH), 0, stream, W0, Ws, W0b, Wsb);
  hipLaunchKernelGGL(flow_fused, dim3(B_ROWS / BM), dim3(NTH), 0, stream,
                     z, h, W0b, b0, Wsb, bs, out);
}

// Round 4
// 134.687 us; speedup vs baseline: 1.4575x; 1.4575x over previous
//
#include <hip/hip_runtime.h>

typedef __attribute__((ext_vector_type(4))) float f32x4;
typedef __attribute__((ext_vector_type(8))) short bf16x8;
typedef __attribute__((ext_vector_type(2))) unsigned int u32x2;
typedef __attribute__((ext_vector_type(4))) unsigned int u32x4;
typedef unsigned short ushort_t;

#define B_ROWS 65536
#define L_DIM  256
#define H_IN_D 300
#define H_PAD  320
#define BM     64
#define LDW    328   // unified LDS buffer stride in ushorts (>=320, 656B/row, 2-way banks)
#define NTH    256

__device__ __forceinline__ ushort_t f2bf(float f) {
  unsigned u = __builtin_bit_cast(unsigned, f);
  unsigned r = u + 0x7fffu + ((u >> 16) & 1u);   // RNE, no NaN in data
  return (ushort_t)(r >> 16);
}
__device__ __forceinline__ unsigned pk2(float lo, float hi) {
  return (unsigned)f2bf(lo) | ((unsigned)f2bf(hi) << 16);
}
__device__ __forceinline__ float bflo(unsigned u) { return __builtin_bit_cast(float, u << 16); }
__device__ __forceinline__ float bfhi(unsigned u) { return __builtin_bit_cast(float, u & 0xffff0000u); }

// ---------------- weight pre-conversion (once per launch) ----------------
__global__ void cvt_w(const float* __restrict__ W0, const float* __restrict__ Ws,
                      ushort_t* __restrict__ W0b, ushort_t* __restrict__ Wsb) {
  int i = blockIdx.x * blockDim.x + threadIdx.x;
  int stride = gridDim.x * blockDim.x;
  for (int t = i; t < 256 * H_PAD; t += stride) {
    int n = t / H_PAD, k = t - n * H_PAD;
    W0b[t] = (k < H_IN_D) ? f2bf(W0[n * H_IN_D + k]) : (ushort_t)0;
  }
  for (int t = i; t < 3 * 256 * 256; t += stride) Wsb[t] = f2bf(Ws[t]);
}

// ---------------- fused flow kernel ----------------
// Swapped-operand GEMM: X = W rows (16 n's / tile), Y = v/h rows (16 m's / tile).
// mfma(x, y, acc): D reg j, lane (r,g) -> n = nt*16 + g*4 + j (X row dim),
//                                         m = mt*16 + r      (Y row dim).
// So the epilogue writes 4 CONSECUTIVE output cols per lane -> ds_write_b64.
template<int KSTEPS>
__device__ __forceinline__ void gemm_acc(
    const ushort_t* __restrict__ Slds,     // Y source [64][LDW], rows m
    const ushort_t* __restrict__ Wg, int ldb,  // X source, rows n (global bf16)
    int wave, int r, int g, f32x4 (&acc)[4][4])
{
  const ushort_t* xb = Wg + (wave * 64 + r) * ldb + g * 8;
  const ushort_t* yb = Slds + r * LDW + g * 8;
#pragma unroll
  for (int ks = 0; ks < KSTEPS; ++ks) {
    bf16x8 x[4];
#pragma unroll
    for (int nt = 0; nt < 4; ++nt) x[nt] = *(const bf16x8*)(xb + nt * 16 * ldb + ks * 32);
    bf16x8 y[4];
#pragma unroll
    for (int mt = 0; mt < 4; ++mt) y[mt] = *(const bf16x8*)(yb + mt * 16 * LDW + ks * 32);
#pragma unroll
    for (int nt = 0; nt < 4; ++nt) {
      acc[nt][0] = __builtin_amdgcn_mfma_f32_16x16x32_bf16(x[nt], y[0], acc[nt][0], 0, 0, 0);
      acc[nt][1] = __builtin_amdgcn_mfma_f32_16x16x32_bf16(x[nt], y[1], acc[nt][1], 0, 0, 0);
      acc[nt][2] = __builtin_amdgcn_mfma_f32_16x16x32_bf16(x[nt], y[2], acc[nt][2], 0, 0, 0);
      acc[nt][3] = __builtin_amdgcn_mfma_f32_16x16x32_bf16(x[nt], y[3], acc[nt][3], 0, 0, 0);
    }
  }
}

// epilogue: +bias, pack bf16 pairs, vector ds_write_b64 (4 consecutive cols/lane)
__device__ __forceinline__ void epi_write(
    f32x4 (&acc)[4][4], const float* __restrict__ bias,
    ushort_t* __restrict__ Slds, int wave, int r, int g)
{
#pragma unroll
  for (int nt = 0; nt < 4; ++nt) {
    const int n0 = wave * 64 + nt * 16 + g * 4;
    f32x4 bv = *(const f32x4*)(bias + n0);
#pragma unroll
    for (int mt = 0; mt < 4; ++mt) {
      float v0 = acc[nt][mt][0] + bv[0];
      float v1 = acc[nt][mt][1] + bv[1];
      float v2 = acc[nt][mt][2] + bv[2];
      float v3 = acc[nt][mt][3] + bv[3];
      u32x2 p; p[0] = pk2(v0, v1); p[1] = pk2(v2, v3);
      *(u32x2*)&Slds[(mt * 16 + r) * LDW + n0] = p;
    }
  }
}

// Householder: z -= 2 v (v.z)/(v.v). Row = wave*16 + r; lane owns cols
// g*64 .. g*64+63. Reduce across the 4 lanes sharing a row: shfl_xor 16, 32.
__device__ __forceinline__ void dot_update(const ushort_t* __restrict__ V,
                                           int wave, int r, int g, float (&zr)[64])
{
  const ushort_t* vp = V + (wave * 16 + r) * LDW + g * 64;
  float vz = 0.f, vv = 0.f;
#pragma unroll
  for (int jb = 0; jb < 8; ++jb) {
    u32x4 q = *(const u32x4*)(vp + jb * 8);
#pragma unroll
    for (int w = 0; w < 4; ++w) {
      unsigned u = q[w];
      float f0 = bflo(u), f1 = bfhi(u);
      int i = jb * 8 + w * 2;
      vz = fmaf(f0, zr[i], vz);     vv = fmaf(f0, f0, vv);
      vz = fmaf(f1, zr[i + 1], vz); vv = fmaf(f1, f1, vv);
    }
  }
  vz += __shfl_xor(vz, 16); vv += __shfl_xor(vv, 16);
  vz += __shfl_xor(vz, 32); vv += __shfl_xor(vv, 32);
  float a = 2.f * vz / vv;
#pragma unroll
  for (int jb = 0; jb < 8; ++jb) {
    u32x4 q = *(const u32x4*)(vp + jb * 8);
#pragma unroll
    for (int w = 0; w < 4; ++w) {
      unsigned u = q[w];
      int i = jb * 8 + w * 2;
      zr[i]     = fmaf(-a, bflo(u), zr[i]);
      zr[i + 1] = fmaf(-a, bfhi(u), zr[i + 1]);
    }
  }
}

__global__ __launch_bounds__(NTH, 2) void flow_fused(
    const float* __restrict__ z, const float* __restrict__ h,
    const ushort_t* __restrict__ W0b, const float* __restrict__ b0,
    const ushort_t* __restrict__ Wsb, const float* __restrict__ bs,
    float* __restrict__ out)
{
  // Single unified LDS buffer [64][328] bf16 = 41984 B -> 3 blocks/CU.
  // Holds h (cols 0..319) during stage 1, then v (cols 0..255) per stage.
  // Trick: k-loop reads S into reg acc -> barrier -> epilogue overwrites S.
  __shared__ __align__(16) ushort_t S[BM * LDW];

  const int tid  = threadIdx.x;
  const int wave = tid >> 6;
  const int lane = tid & 63;
  const int r    = lane & 15;
  const int g    = lane >> 4;
  const int row0 = blockIdx.x * BM;

  // ---- stage h -> S as bf16, K padded 300->320 with zeros (vectorized) ----
  for (int row = wave; row < BM; row += 4) {
    const float* hrow = h + (row0 + row) * H_IN_D;
    // cols 0..255: lane reads f32x4 at col 4*lane
    f32x4 m4 = *(const f32x4*)(hrow + 4 * lane);
    u32x2 pm; pm[0] = pk2(m4[0], m4[1]); pm[1] = pk2(m4[2], m4[3]);
    *(u32x2*)&S[row * LDW + 4 * lane] = pm;
    // cols 256..319: lanes 0..10 real data (256..299), lanes 11..15 zeros
    if (lane < 16) {
      f32x4 t4 = {0.f, 0.f, 0.f, 0.f};
      if (lane < 11) t4 = *(const f32x4*)(hrow + 256 + 4 * lane);
      u32x2 pt; pt[0] = pk2(t4[0], t4[1]); pt[1] = pk2(t4[2], t4[3]);
      *(u32x2*)&S[row * LDW + 256 + 4 * lane] = pt;
    }
  }

  // ---- load z tile into registers (row = wave*16 + r, 64 cols/lane) ----
  float zr[64];
  const int zrow = wave * 16 + r;
  {
    const float* zp = z + (row0 + zrow) * L_DIM + g * 64;
#pragma unroll
    for (int j = 0; j < 16; ++j) {
      f32x4 v = *(const f32x4*)(zp + j * 4);
      zr[j * 4 + 0] = v[0]; zr[j * 4 + 1] = v[1];
      zr[j * 4 + 2] = v[2]; zr[j * 4 + 3] = v[3];
    }
  }

  __syncthreads();

  // ---- stage 1: v1 = h @ W0^T + b0 (K=320 padded) ----
  {
    f32x4 acc[4][4];
#pragma unroll
    for (int a = 0; a < 4; ++a)
#pragma unroll
      for (int b = 0; b < 4; ++b) { acc[a][b][0]=0.f; acc[a][b][1]=0.f; acc[a][b][2]=0.f; acc[a][b][3]=0.f; }
    gemm_acc<10>(S, W0b, H_PAD, wave, r, g, acc);
    __syncthreads();                 // all reads of h done
    epi_write(acc, b0, S, wave, r, g);
  }
  __syncthreads();                   // v1 visible
  dot_update(S, wave, r, g, zr);

  // ---- stages 2..4: v = v @ Ws[s]^T + bs[s], all in-place in S ----
#pragma unroll
  for (int s = 0; s < 3; ++s) {
    f32x4 acc[4][4];
#pragma unroll
    for (int a = 0; a < 4; ++a)
#pragma unroll
      for (int b = 0; b < 4; ++b) { acc[a][b][0]=0.f; acc[a][b][1]=0.f; acc[a][b][2]=0.f; acc[a][b][3]=0.f; }
    gemm_acc<8>(S, Wsb + s * 256 * 256, 256, wave, r, g, acc);
    __syncthreads();                 // all reads of v_s done (dot already done too)
    epi_write(acc, bs + s * 256, S, wave, r, g);
    __syncthreads();                 // v_{s+1} visible
    dot_update(S, wave, r, g, zr);
  }

  // ---- store z ----
  {
    float* op = out + (row0 + zrow) * L_DIM + g * 64;
#pragma unroll
    for (int j = 0; j < 16; ++j) {
      f32x4 v;
      v[0] = zr[j * 4 + 0]; v[1] = zr[j * 4 + 1];
      v[2] = zr[j * 4 + 2]; v[3] = zr[j * 4 + 3];
      *(f32x4*)(op + j * 4) = v;
    }
  }
}

extern "C" void kernel_launch(void* const* d_in, const int* in_sizes, int n_in,
                              void* d_out, int out_size, void* d_ws, size_t ws_size,
                              hipStream_t stream) {
  const float* z  = (const float*)d_in[0];
  const float* h  = (const float*)d_in[1];
  const float* W0 = (const float*)d_in[2];
  const float* b0 = (const float*)d_in[3];
  const float* Ws = (const float*)d_in[4];
  const float* bs = (const float*)d_in[5];
  float* out = (float*)d_out;

  ushort_t* W0b = (ushort_t*)d_ws;            // 256*320 bf16 = 163840 B
  ushort_t* Wsb = W0b + 256 * H_PAD;          // 3*256*256 bf16 = 393216 B

  hipLaunchKernelGGL(cvt_w, dim3(256), dim3(NTH), 0, stream, W0, Ws, W0b, Wsb);
  hipLaunchKernelGGL(flow_fused, dim3(B_ROWS / BM), dim3(NTH), 0, stream,
                     z, h, W0b, b0, Wsb, bs, out);
}